// Round 18
// baseline (3479.526 us; speedup 1.0000x reference)
//
#include <hip/hip_runtime.h>

#define N      8192
#define KDIM   64
// base-2 scaled constants
#define SCALE2     28.853900817779268f    // 20 / ln2
#define INV_SCALE2 0.034657359027997264f  // ln2 / 20
#define TWOSCALE   57.707801635558536f    // 40 / ln2
#define EPSLN2     0.034657359027997264f  // 0.05 * ln2
#define EPS_LOG_MU (-0.45054566736396444f)
#define THRESH     0.001f
#define NEG_BIG    (-1e30f)
#define DEFER_THR  8.0f      // T13 defer-max threshold (base-2)
#define NCHUNK  32           // col chunks
#define COLSPAN 256          // cols per chunk
#define NCT     16           // 16-col tiles per chunk
#define NBUF    5            // LDS tile buffers (4 tiles in flight)
#define ROWS_PER_BLOCK 256   // 4 waves x 64 rows

typedef __attribute__((ext_vector_type(8))) short bf16x8;
typedef __attribute__((ext_vector_type(4))) float f32x4;

static __device__ __forceinline__ float exp2fast(float x) { return __builtin_amdgcn_exp2f(x); }
static __device__ __forceinline__ float log2fast(float x) { return __builtin_amdgcn_logf(x); }

static __device__ __forceinline__ unsigned short f2bf(float f) {
    unsigned u = __float_as_uint(f);
    u += 0x7FFFu + ((u >> 16) & 1u);
    return (unsigned short)(u >> 16);
}
static __device__ __forceinline__ float bf2f(unsigned short h) {
    return __uint_as_float(((unsigned)h) << 16);
}

// async 16B/lane global -> LDS (dest = wave-uniform base + lane*16)
static __device__ __forceinline__ void load16_to_lds(const void* gptr, void* lptr) {
    __builtin_amdgcn_global_load_lds(
        (const __attribute__((address_space(1))) unsigned int*)gptr,
        (__attribute__((address_space(3))) unsigned int*)lptr,
        16, 0, 0);
}

// Stage one 16-col tile (hi 2KB + lo 2KB) into a 4KB LDS buffer; wave w moves
// piece w (1KB) = exactly ONE global_load_lds per wave (vmcnt +1). Global
// source pre-swizzled: LDS slot s' of col c holds global slot s = s'^(c&7)
// (bank-conflict-free reads; LDS dest stays linear as global_load_lds needs).
static __device__ __forceinline__ void stage_tile(
        const unsigned short* __restrict__ CPhi, const unsigned short* __restrict__ CPlo,
        char* ldsbuf, int jb, int wave, int swz) {
    const char* gsrc = (const char*)(wave < 2 ? CPhi : CPlo);
    const char* g = gsrc + (size_t)jb * 128 + (size_t)((wave & 1) * 1024 + swz);
    char* l = ldsbuf + (wave & 1) * 1024 + (wave >> 1) * 2048;
    load16_to_lds(g, l);
}

// held RP fragments: 4 row-tiles x 2 k-steps, hi+lo (64 regs; unified VGPR/AGPR)
static __device__ __forceinline__ void load_held(
        const unsigned short* __restrict__ RPhi, const unsigned short* __restrict__ RPlo,
        int rowbase, int lrow, int kgrp, bf16x8 (&bh)[4][2], bf16x8 (&bl)[4][2]) {
#pragma unroll
    for (int it = 0; it < 4; ++it)
#pragma unroll
        for (int ks = 0; ks < 2; ++ks) {
            int boff = (rowbase + it * 16 + lrow) * KDIM + ks * 32 + kgrp * 8;
            bh[it][ks] = *reinterpret_cast<const bf16x8*>(RPhi + boff);
            bl[it][ks] = *reinterpret_cast<const bf16x8*>(RPlo + boff);
            asm volatile("" : "+v"(bh[it][ks]));
            asm volatile("" : "+v"(bl[it][ks]));
        }
}

// lgkmcnt-only prologue barrier: orders LDS writes (alpha etc.) across the
// block WITHOUT draining the in-flight global_load_lds prefetch (vmcnt).
static __device__ __forceinline__ void barrier_lds_only() {
    asm volatile("s_waitcnt lgkmcnt(0)" ::: "memory");
    __builtin_amdgcn_sched_barrier(0);
    __builtin_amdgcn_s_barrier();
    __builtin_amdgcn_sched_barrier(0);
}

// Counted-vmcnt pipeline barrier (T4): waits until <= n of this wave's stages
// outstanding (n constant-folds under #pragma unroll), leaving newer prefetch
// in flight across the barrier.
static __device__ __forceinline__ void pipe_wait(int n) {
    if (n >= 3)      asm volatile("s_waitcnt vmcnt(3)" ::: "memory");
    else if (n == 2) asm volatile("s_waitcnt vmcnt(2)" ::: "memory");
    else if (n == 1) asm volatile("s_waitcnt vmcnt(1)" ::: "memory");
    else             asm volatile("s_waitcnt vmcnt(0)" ::: "memory");
    __builtin_amdgcn_sched_barrier(0);
    __builtin_amdgcn_s_barrier();
    __builtin_amdgcn_sched_barrier(0);
}

// Main fused cost+LSE loop (round-16 structure + T13 defer-max epilogue).
// 3-term split-bf16 dot. A (cols) streamed via 5-buffer LDS pipeline; B (64
// rows) held in registers. setprio(1) around MFMA cluster (T5).
// Defer-max: when NO lane's tile max exceeds m+THR, skip the rescale exp2 and
// keep the old max (P bounded by 2^THR; s <= 2^16 -> fp32-safe).
// Caller must have staged tiles 0..3 (into bufs 0..3) before entry.
static __device__ __forceinline__ void lse_loop(
        const unsigned short* __restrict__ CPhi, const unsigned short* __restrict__ CPlo,
        char* ldsA, const float* lds_alpha,
        const bf16x8 (&bh)[4][2], const bf16x8 (&bl)[4][2],
        int jbase0, int wave, int lane, int swz, float (&m)[4], float (&s)[4]) {
    const int lrow = lane & 15, kgrp = lane >> 4;
    const int ro = lrow * 128;
    const int x0 = ((kgrp)     ^ (lrow & 7)) * 16;
    const int x1 = ((kgrp + 4) ^ (lrow & 7)) * 16;
#pragma unroll
    for (int ct = 0; ct < NCT; ++ct) {
        int w = NCT - 1 - ct; if (w > 3) w = 3;
        pipe_wait(w);                      // tile ct resident for ALL waves
        if (ct + 4 < NCT)                  // refill buf (ct+4)%5 == (ct-1)%5
            stage_tile(CPhi, CPlo, ldsA + ((ct + 4) % NBUF) * 4096,
                       jbase0 + (ct + 4) * 16, wave, swz);

        float4 av = *reinterpret_cast<const float4*>(lds_alpha + ct * 16 + kgrp * 4);
        const char* base = ldsA + (ct % NBUF) * 4096;
        bf16x8 ah0 = *reinterpret_cast<const bf16x8*>(base + ro + x0);
        bf16x8 ah1 = *reinterpret_cast<const bf16x8*>(base + ro + x1);
        bf16x8 al0 = *reinterpret_cast<const bf16x8*>(base + 2048 + ro + x0);
        bf16x8 al1 = *reinterpret_cast<const bf16x8*>(base + 2048 + ro + x1);

        __builtin_amdgcn_s_setprio(1);
        f32x4 acc[4];
#pragma unroll
        for (int it = 0; it < 4; ++it) {
            f32x4 a = {0.0f, 0.0f, 0.0f, 0.0f};
            a = __builtin_amdgcn_mfma_f32_16x16x32_bf16(ah0, bh[it][0], a, 0, 0, 0);
            a = __builtin_amdgcn_mfma_f32_16x16x32_bf16(ah1, bh[it][1], a, 0, 0, 0);
            a = __builtin_amdgcn_mfma_f32_16x16x32_bf16(al0, bh[it][0], a, 0, 0, 0);
            a = __builtin_amdgcn_mfma_f32_16x16x32_bf16(al1, bh[it][1], a, 0, 0, 0);
            a = __builtin_amdgcn_mfma_f32_16x16x32_bf16(ah0, bl[it][0], a, 0, 0, 0);
            a = __builtin_amdgcn_mfma_f32_16x16x32_bf16(ah1, bl[it][1], a, 0, 0, 0);
            acc[it] = a;
        }
        __builtin_amdgcn_s_setprio(0);

#pragma unroll
        for (int it = 0; it < 4; ++it) {
            float L0 = fmaf(TWOSCALE, acc[it][0], av.x);
            float L1 = fmaf(TWOSCALE, acc[it][1], av.y);
            float L2 = fmaf(TWOSCALE, acc[it][2], av.z);
            float L3 = fmaf(TWOSCALE, acc[it][3], av.w);
            float mx = fmaxf(fmaxf(L0, L1), fmaxf(L2, L3));
            if (__all(mx <= m[it] + DEFER_THR)) {
                // fast path: max unchanged, no rescale exp2, no m update
                s[it] += (exp2fast(L0 - m[it]) + exp2fast(L1 - m[it])) +
                         (exp2fast(L2 - m[it]) + exp2fast(L3 - m[it]));
            } else {
                float mn = fmaxf(m[it], mx);
                float rs = exp2fast(m[it] - mn);
                float e  = (exp2fast(L0 - mn) + exp2fast(L1 - mn)) +
                           (exp2fast(L2 - mn) + exp2fast(L3 - mn));
                s[it] = fmaf(s[it], rs, e);
                m[it] = mn;
            }
        }
    }
}

static __device__ __forceinline__ void write_partials(
        float (&m)[4], float (&s)[4], float* __restrict__ pm, float* __restrict__ ps,
        const float* __restrict__ sqr2, int ck, int rowbase, int lane) {
    const int lrow = lane & 15, kgrp = lane >> 4;
#pragma unroll
    for (int off = 16; off < 64; off <<= 1) {
#pragma unroll
        for (int it = 0; it < 4; ++it) {
            float mo = __shfl_xor(m[it], off);
            float so = __shfl_xor(s[it], off);
            float mn = fmaxf(m[it], mo);
            s[it] = s[it] * exp2fast(m[it] - mn) + so * exp2fast(mo - mn);
            m[it] = mn;
        }
    }
    if (kgrp == 0) {
#pragma unroll
        for (int it = 0; it < 4; ++it) {
            int row = rowbase + it * 16 + lrow;
            pm[(size_t)ck * N + row] = m[it] - sqr2[row];
            ps[(size_t)ck * N + row] = s[it];
        }
    }
}

// uniform convergence self-check: sum the 32 blockDiff entries written by the
// previous col pass (stable during this dispatch; kernels serialize on stream)
static __device__ __forceinline__ bool conv_done(const float* __restrict__ bd) {
    float sd = 0.0f;
#pragma unroll
    for (int c = 0; c < 32; ++c) sd += bd[c];
    return sd * (1.0f / (float)N) < THRESH;
}

// ---------------- setup kernels ----------------
__global__ void norms_kernel(const float* __restrict__ S, const float* __restrict__ T,
                             float* __restrict__ sq_s2, float* __restrict__ sq_t2) {
    int t = blockIdx.x * blockDim.x + threadIdx.x;
    const float* p = (t < N) ? S : T;
    int r = t & (N - 1);
    const float4* row = reinterpret_cast<const float4*>(p + (size_t)r * KDIM);
    float acc = 0.0f;
#pragma unroll
    for (int q = 0; q < KDIM / 4; ++q) {
        float4 a = row[q];
        acc += a.x * a.x + a.y * a.y + a.z * a.z + a.w * a.w;
    }
    if (t < N) sq_s2[r] = acc * SCALE2; else sq_t2[r] = acc * SCALE2;
}

__global__ void init_kernel(float* u, float* v, float* blockDiff) {
    int t = blockIdx.x * blockDim.x + threadIdx.x;
    if (t < N) { u[t] = 0.0f; v[t] = 0.0f; }
    if (t < 128) blockDiff[t] = 1.0e9f;   // both ping-pong slots: "not converged"
}

__global__ void split_kernel(const float* __restrict__ S, const float* __restrict__ T,
                             unsigned short* __restrict__ Shi, unsigned short* __restrict__ Slo,
                             unsigned short* __restrict__ Thi, unsigned short* __restrict__ Tlo) {
    int t = blockIdx.x * 256 + threadIdx.x;
    const int half = (N * KDIM) / 4;
    const float* src = (t < half) ? S : T;
    unsigned short* dhi = (t < half) ? Shi : Thi;
    unsigned short* dlo = (t < half) ? Slo : Tlo;
    int e = (t < half) ? t : t - half;
    float4 x = reinterpret_cast<const float4*>(src)[e];
    unsigned short h0 = f2bf(x.x), h1 = f2bf(x.y), h2 = f2bf(x.z), h3 = f2bf(x.w);
    ushort4 hv = make_ushort4(h0, h1, h2, h3);
    ushort4 lv = make_ushort4(f2bf(x.x - bf2f(h0)), f2bf(x.y - bf2f(h1)),
                              f2bf(x.z - bf2f(h2)), f2bf(x.w - bf2f(h3)));
    reinterpret_cast<ushort4*>(dhi)[e] = hv;
    reinterpret_cast<ushort4*>(dlo)[e] = lv;
}

// ---------------- row pass (v->alpha reduce fused into prologue) ----------------
__global__ __launch_bounds__(256, 4) void row_lse(
        const unsigned short* __restrict__ CPhi, const unsigned short* __restrict__ CPlo,
        const unsigned short* __restrict__ RPhi, const unsigned short* __restrict__ RPlo,
        const float* __restrict__ pmV, const float* __restrict__ psV,  // prev col partials
        const float* __restrict__ sqc2,   // streamed-side norms
        const float* __restrict__ sqr2,   // held-side norms
        float* __restrict__ pm, float* __restrict__ ps,
        const float* __restrict__ bdPrev, int first) {
    if (!first && conv_done(bdPrev)) return;
    __shared__ __align__(16) char ldsA[NBUF * 4096];
    __shared__ __align__(16) float lds_alpha[COLSPAN];
    const int wave = threadIdx.x >> 6, lane = threadIdx.x & 63;
    const int lrow = lane & 15, kgrp = lane >> 4;
    const int ck = blockIdx.x & 31, rb = blockIdx.x >> 5;
    const int rowbase = rb * ROWS_PER_BLOCK + wave * 64;
    const int jbase0 = ck * COLSPAN;
    const int swz = (lane >> 3) * 128 + (((lane & 7) ^ ((lane >> 3) & 7)) << 4);

#pragma unroll
    for (int t = 0; t < 4; ++t)   // tiles 0..3 -> bufs 0..3
        stage_tile(CPhi, CPlo, ldsA + t * 4096, jbase0 + t * 16, wave, swz);

    // fused v->alpha reduce for this block's 256 streamed cols (overlaps stage)
    {
        int j = jbase0 + threadIdx.x;
        float a;
        if (first) {
            a = -sqc2[j];                 // v = 0
        } else {
            float mm = NEG_BIG, ss = 0.0f;
#pragma unroll
            for (int c = 0; c < NCHUNK; ++c) {
                float mc = pmV[(size_t)c * N + j];
                float sc = psV[(size_t)c * N + j];
                float mn = fmaxf(mm, mc);
                ss = ss * exp2fast(mm - mn) + sc * exp2fast(mc - mn);
                mm = mn;
            }
            float vnew = EPS_LOG_MU - EPSLN2 * (mm + log2fast(ss));
            a = fmaf(vnew, SCALE2, -sqc2[j]);
        }
        lds_alpha[threadIdx.x] = a;
    }

    bf16x8 bh[4][2], bl[4][2];
    load_held(RPhi, RPlo, rowbase, lrow, kgrp, bh, bl);

    float m[4] = {NEG_BIG, NEG_BIG, NEG_BIG, NEG_BIG};
    float s[4] = {0.0f, 0.0f, 0.0f, 0.0f};
    barrier_lds_only();   // alpha visible; prefetch stays in flight

    lse_loop(CPhi, CPlo, ldsA, lds_alpha, bh, bl, jbase0, wave, lane, swz, m, s);
    write_partials(m, s, pm, ps, sqr2, ck, rowbase, lane);
}

// ---------------- col pass (u-reduce fused; writes diff to bdCur) ----------------
__global__ __launch_bounds__(256, 4) void col_lse(
        const unsigned short* __restrict__ CPhi, const unsigned short* __restrict__ CPlo,
        const unsigned short* __restrict__ RPhi, const unsigned short* __restrict__ RPlo,
        const float* __restrict__ pm_in, const float* __restrict__ ps_in,
        const float* __restrict__ sqs2,   // streamed-side norms (alpha)
        float* __restrict__ u,            // rw by rb==0 blocks only
        const float* __restrict__ bdPrev,
        float* __restrict__ bdCur,
        const float* __restrict__ sqr2,   // held-side norms (partial write)
        float* __restrict__ pm, float* __restrict__ ps) {
    const int ck = blockIdx.x & 31, rb = blockIdx.x >> 5;
    if (conv_done(bdPrev)) {
        if (rb == 0 && threadIdx.x == 0) bdCur[ck] = 0.0f;   // latch convergence
        return;
    }
    __shared__ __align__(16) char ldsA[NBUF * 4096];
    __shared__ __align__(16) float lds_alpha[COLSPAN];
    __shared__ float wsum[4];
    const int wave = threadIdx.x >> 6, lane = threadIdx.x & 63;
    const int lrow = lane & 15, kgrp = lane >> 4;
    const int rowbase = rb * ROWS_PER_BLOCK + wave * 64;
    const int jbase0 = ck * COLSPAN;
    const int swz = (lane >> 3) * 128 + (((lane & 7) ^ ((lane >> 3) & 7)) << 4);

#pragma unroll
    for (int t = 0; t < 4; ++t)
        stage_tile(CPhi, CPlo, ldsA + t * 4096, jbase0 + t * 16, wave, swz);

    // fused u-reduce for this block's 256 streamed cols (overlaps stage latency)
    {
        int j = jbase0 + threadIdx.x;
        float mm = NEG_BIG, ss = 0.0f;
#pragma unroll
        for (int c = 0; c < NCHUNK; ++c) {
            float mc = pm_in[(size_t)c * N + j];
            float sc = ps_in[(size_t)c * N + j];
            float mn = fmaxf(mm, mc);
            ss = ss * exp2fast(mm - mn) + sc * exp2fast(mc - mn);
            mm = mn;
        }
        float unew = EPS_LOG_MU - EPSLN2 * (mm + log2fast(ss));
        lds_alpha[threadIdx.x] = fmaf(unew, SCALE2, -sqs2[j]);
        if (rb == 0) {
            float d = fabsf(unew - u[j]);
            u[j] = unew;
#pragma unroll
            for (int off = 32; off; off >>= 1) d += __shfl_xor(d, off);
            if (lane == 0) wsum[wave] = d;
        }
    }

    bf16x8 bh[4][2], bl[4][2];
    load_held(RPhi, RPlo, rowbase, lrow, kgrp, bh, bl);

    float m[4] = {NEG_BIG, NEG_BIG, NEG_BIG, NEG_BIG};
    float s[4] = {0.0f, 0.0f, 0.0f, 0.0f};
    barrier_lds_only();
    if (rb == 0 && threadIdx.x == 0)
        bdCur[ck] = wsum[0] + wsum[1] + wsum[2] + wsum[3];

    lse_loop(CPhi, CPlo, ldsA, lds_alpha, bh, bl, jbase0, wave, lane, swz, m, s);
    write_partials(m, s, pm, ps, sqr2, ck, rowbase, lane);
}

// ---------------- post-loop: reduce final pmB/psB -> v ----------------
__global__ __launch_bounds__(256) void v_final(const float* __restrict__ pm,
                                               const float* __restrict__ ps,
                                               float* __restrict__ v) {
    int j = blockIdx.x * 256 + threadIdx.x;
    float m = NEG_BIG, s = 0.0f;
#pragma unroll
    for (int c = 0; c < NCHUNK; ++c) {
        float mc = pm[(size_t)c * N + j];
        float sc = ps[(size_t)c * N + j];
        float mn = fmaxf(m, mc);
        s = s * exp2fast(m - mn) + sc * exp2fast(mc - mn);
        m = mn;
    }
    v[j] = EPS_LOG_MU - EPSLN2 * (m + log2fast(s));
}

// ---------------- final: sum(exp((u+v-c)/eps) * c), same approx cost ----------------
__global__ __launch_bounds__(256, 4) void plan_mfma(
        const unsigned short* __restrict__ CPhi, const unsigned short* __restrict__ CPlo,  // T
        const unsigned short* __restrict__ RPhi, const unsigned short* __restrict__ RPlo,  // S
        const float* __restrict__ u, const float* __restrict__ v,
        const float* __restrict__ sqr2, const float* __restrict__ sqc2,
        float* __restrict__ part) {
    __shared__ __align__(16) char ldsA[NBUF * 4096];
    __shared__ __align__(16) float lds_v2[COLSPAN];
    __shared__ __align__(16) float lds_sqc[COLSPAN];
    __shared__ float wsum[4];
    const int wave = threadIdx.x >> 6, lane = threadIdx.x & 63;
    const int lrow = lane & 15, kgrp = lane >> 4;
    const int ck = blockIdx.x & 31, rb = blockIdx.x >> 5;
    const int rowbase = rb * ROWS_PER_BLOCK + wave * 64;
    const int jbase0 = ck * COLSPAN;
    const int swz = (lane >> 3) * 128 + (((lane & 7) ^ ((lane >> 3) & 7)) << 4);

#pragma unroll
    for (int t = 0; t < 4; ++t)
        stage_tile(CPhi, CPlo, ldsA + t * 4096, jbase0 + t * 16, wave, swz);
    lds_v2[threadIdx.x]  = v[jbase0 + threadIdx.x] * SCALE2;
    lds_sqc[threadIdx.x] = sqc2[jbase0 + threadIdx.x];

    bf16x8 bh[4][2], bl[4][2];
    load_held(RPhi, RPlo, rowbase, lrow, kgrp, bh, bl);

    float sqr_i[4], u2_i[4];
#pragma unroll
    for (int it = 0; it < 4; ++it) {
        int row = rowbase + it * 16 + lrow;
        sqr_i[it] = sqr2[row];
        u2_i[it]  = u[row] * SCALE2;
    }

    float lsum = 0.0f;
    barrier_lds_only();

    const int ro = lrow * 128;
    const int x0 = ((kgrp)     ^ (lrow & 7)) * 16;
    const int x1 = ((kgrp + 4) ^ (lrow & 7)) * 16;
#pragma unroll
    for (int ct = 0; ct < NCT; ++ct) {
        int w = NCT - 1 - ct; if (w > 3) w = 3;
        pipe_wait(w);
        if (ct + 4 < NCT)
            stage_tile(CPhi, CPlo, ldsA + ((ct + 4) % NBUF) * 4096,
                       jbase0 + (ct + 4) * 16, wave, swz);

        float4 v2 = *reinterpret_cast<const float4*>(lds_v2 + ct * 16 + kgrp * 4);
        float4 sc = *reinterpret_cast<const float4*>(lds_sqc + ct * 16 + kgrp * 4);
        const char* base = ldsA + (ct % NBUF) * 4096;
        bf16x8 ah0 = *reinterpret_cast<const bf16x8*>(base + ro + x0);
        bf16x8 ah1 = *reinterpret_cast<const bf16x8*>(base + ro + x1);
        bf16x8 al0 = *reinterpret_cast<const bf16x8*>(base + 2048 + ro + x0);
        bf16x8 al1 = *reinterpret_cast<const bf16x8*>(base + 2048 + ro + x1);

        __builtin_amdgcn_s_setprio(1);
        f32x4 acc[4];
#pragma unroll
        for (int it = 0; it < 4; ++it) {
            f32x4 a = {0.0f, 0.0f, 0.0f, 0.0f};
            a = __builtin_amdgcn_mfma_f32_16x16x32_bf16(ah0, bh[it][0], a, 0, 0, 0);
            a = __builtin_amdgcn_mfma_f32_16x16x32_bf16(ah1, bh[it][1], a, 0, 0, 0);
            a = __builtin_amdgcn_mfma_f32_16x16x32_bf16(al0, bh[it][0], a, 0, 0, 0);
            a = __builtin_amdgcn_mfma_f32_16x16x32_bf16(al1, bh[it][1], a, 0, 0, 0);
            a = __builtin_amdgcn_mfma_f32_16x16x32_bf16(ah0, bl[it][0], a, 0, 0, 0);
            a = __builtin_amdgcn_mfma_f32_16x16x32_bf16(ah1, bl[it][1], a, 0, 0, 0);
            acc[it] = a;
        }
        __builtin_amdgcn_s_setprio(0);

        float vs[4] = {v2.x, v2.y, v2.z, v2.w};
        float ss[4] = {sc.x, sc.y, sc.z, sc.w};
#pragma unroll
        for (int it = 0; it < 4; ++it) {
#pragma unroll
            for (int r = 0; r < 4; ++r) {
                float c2 = fmaxf(sqr_i[it] + ss[r] - TWOSCALE * acc[it][r], 0.0f);
                lsum = fmaf(exp2fast(u2_i[it] + vs[r] - c2), c2, lsum);
            }
        }
    }
    lsum *= INV_SCALE2;

#pragma unroll
    for (int off = 32; off; off >>= 1) lsum += __shfl_xor(lsum, off);
    if (lane == 0) wsum[wave] = lsum;
    __syncthreads();
    if (threadIdx.x == 0)
        part[blockIdx.x] = wsum[0] + wsum[1] + wsum[2] + wsum[3];
}

__global__ void final_reduce(const float* __restrict__ part, float* __restrict__ out) {
    int t = threadIdx.x;
    float sum = 0.0f;
    for (int i = t; i < 1024; i += 256) sum += part[i];
#pragma unroll
    for (int off = 32; off; off >>= 1) sum += __shfl_xor(sum, off);
    __shared__ float wsum[4];
    int lane = t & 63, wave = t >> 6;
    if (lane == 0) wsum[wave] = sum;
    __syncthreads();
    if (t == 0) out[0] = wsum[0] + wsum[1] + wsum[2] + wsum[3];
}

extern "C" void kernel_launch(void* const* d_in, const int* in_sizes, int n_in,
                              void* d_out, int out_size, void* d_ws, size_t ws_size,
                              hipStream_t stream) {
    const float* S = (const float*)d_in[0];
    const float* T = (const float*)d_in[1];
    float* out = (float*)d_out;

    // workspace (~8.3 MB)
    unsigned short* us = (unsigned short*)d_ws;
    unsigned short* Shi = us;
    unsigned short* Slo = us + (size_t)N * KDIM;
    unsigned short* Thi = us + (size_t)2 * N * KDIM;
    unsigned short* Tlo = us + (size_t)3 * N * KDIM;
    float* w = (float*)(us + (size_t)4 * N * KDIM);
    size_t off = 0;
    float* sq_s2     = w + off; off += N;
    float* sq_t2     = w + off; off += N;
    float* u         = w + off; off += N;
    float* v         = w + off; off += N;
    float* pmA       = w + off; off += (size_t)NCHUNK * N;
    float* psA       = w + off; off += (size_t)NCHUNK * N;
    float* pmB       = w + off; off += (size_t)NCHUNK * N;
    float* psB       = w + off; off += (size_t)NCHUNK * N;
    float* blockDiff = w + off; off += 128;   // 2 ping-pong slots of 64
    float* part      = w + off; off += 1024;

    hipLaunchKernelGGL(norms_kernel, dim3(64),   dim3(256), 0, stream, S, T, sq_s2, sq_t2);
    hipLaunchKernelGGL(init_kernel,  dim3(32),   dim3(256), 0, stream, u, v, blockDiff);
    hipLaunchKernelGGL(split_kernel, dim3(1024), dim3(256), 0, stream, S, T, Shi, Slo, Thi, Tlo);

    const int LSE_BLOCKS = (N / ROWS_PER_BLOCK) * NCHUNK;   // 32*32 = 1024
    for (int it = 0; it < 50; ++it) {
        float* bdPrev = blockDiff + ((it + 1) & 1) * 64;
        float* bdCur  = blockDiff + (it & 1) * 64;
        // row pass: stream T cols vs held S rows; v->alpha reduce fused
        hipLaunchKernelGGL(row_lse, dim3(LSE_BLOCKS), dim3(256), 0, stream,
                           Thi, Tlo, Shi, Slo, pmB, psB, sq_t2, sq_s2,
                           pmA, psA, bdPrev, it == 0 ? 1 : 0);
        // col pass: stream S cols vs held T rows; u-reduce fused; diff -> bdCur
        hipLaunchKernelGGL(col_lse, dim3(LSE_BLOCKS), dim3(256), 0, stream,
                           Shi, Slo, Thi, Tlo, pmA, psA, sq_s2, u,
                           bdPrev, bdCur, sq_t2, pmB, psB);
    }

    hipLaunchKernelGGL(v_final, dim3(32), dim3(256), 0, stream, pmB, psB, v);
    hipLaunchKernelGGL(plan_mfma, dim3(LSE_BLOCKS), dim3(256), 0, stream,
                       Thi, Tlo, Shi, Slo, u, v, sq_s2, sq_t2, part);
    hipLaunchKernelGGL(final_reduce, dim3(1), dim3(256), 0, stream, part, out);
}

// Round 19
// 3275.307 us; speedup vs baseline: 1.0624x; 1.0624x over previous
//
#include <hip/hip_runtime.h>

#define N      8192
#define KDIM   64
// base-2 scaled constants
#define SCALE2     28.853900817779268f    // 20 / ln2
#define INV_SCALE2 0.034657359027997264f  // ln2 / 20
#define TWOSCALE   57.707801635558536f    // 40 / ln2
#define EPSLN2     0.034657359027997264f  // 0.05 * ln2
#define EPS_LOG_MU (-0.45054566736396444f)
#define THRESH     0.001f
#define NEG_BIG    (-1e30f)
#define NCHUNK  32           // col chunks
#define COLSPAN 256          // cols per chunk
#define NCT     16           // 16-col tiles per chunk
#define NBUF    5            // LDS tile buffers (4 tiles in flight)
#define ROWS_PER_BLOCK 256   // 4 waves x 64 rows

typedef __attribute__((ext_vector_type(8))) short bf16x8;
typedef __attribute__((ext_vector_type(4))) float f32x4;

static __device__ __forceinline__ float exp2fast(float x) { return __builtin_amdgcn_exp2f(x); }
static __device__ __forceinline__ float log2fast(float x) { return __builtin_amdgcn_logf(x); }

static __device__ __forceinline__ unsigned short f2bf(float f) {
    unsigned u = __float_as_uint(f);
    u += 0x7FFFu + ((u >> 16) & 1u);
    return (unsigned short)(u >> 16);
}
static __device__ __forceinline__ float bf2f(unsigned short h) {
    return __uint_as_float(((unsigned)h) << 16);
}

// async 16B/lane global -> LDS (dest = wave-uniform base + lane*16)
static __device__ __forceinline__ void load16_to_lds(const void* gptr, void* lptr) {
    __builtin_amdgcn_global_load_lds(
        (const __attribute__((address_space(1))) unsigned int*)gptr,
        (__attribute__((address_space(3))) unsigned int*)lptr,
        16, 0, 0);
}

// Stage one 16-col tile (hi 2KB + lo 2KB) into a 4KB LDS buffer; wave w moves
// piece w (1KB) = exactly ONE global_load_lds per wave (vmcnt +1). Global
// source pre-swizzled: LDS slot s' of col c holds global slot s = s'^(c&7)
// (bank-conflict-free reads; LDS dest stays linear as global_load_lds needs).
static __device__ __forceinline__ void stage_tile(
        const unsigned short* __restrict__ CPhi, const unsigned short* __restrict__ CPlo,
        char* ldsbuf, int jb, int wave, int swz) {
    const char* gsrc = (const char*)(wave < 2 ? CPhi : CPlo);
    const char* g = gsrc + (size_t)jb * 128 + (size_t)((wave & 1) * 1024 + swz);
    char* l = ldsbuf + (wave & 1) * 1024 + (wave >> 1) * 2048;
    load16_to_lds(g, l);
}

// held RP fragments: 4 row-tiles x 2 k-steps, hi+lo (64 regs; unified VGPR/AGPR)
static __device__ __forceinline__ void load_held(
        const unsigned short* __restrict__ RPhi, const unsigned short* __restrict__ RPlo,
        int rowbase, int lrow, int kgrp, bf16x8 (&bh)[4][2], bf16x8 (&bl)[4][2]) {
#pragma unroll
    for (int it = 0; it < 4; ++it)
#pragma unroll
        for (int ks = 0; ks < 2; ++ks) {
            int boff = (rowbase + it * 16 + lrow) * KDIM + ks * 32 + kgrp * 8;
            bh[it][ks] = *reinterpret_cast<const bf16x8*>(RPhi + boff);
            bl[it][ks] = *reinterpret_cast<const bf16x8*>(RPlo + boff);
            asm volatile("" : "+v"(bh[it][ks]));
            asm volatile("" : "+v"(bl[it][ks]));
        }
}

// lgkmcnt-only prologue barrier: orders LDS writes (alpha etc.) across the
// block WITHOUT draining the in-flight global_load_lds prefetch (vmcnt).
static __device__ __forceinline__ void barrier_lds_only() {
    asm volatile("s_waitcnt lgkmcnt(0)" ::: "memory");
    __builtin_amdgcn_sched_barrier(0);
    __builtin_amdgcn_s_barrier();
    __builtin_amdgcn_sched_barrier(0);
}

// Counted-vmcnt pipeline barrier (T4): waits until <= n of this wave's stages
// outstanding (n constant-folds under #pragma unroll), leaving newer prefetch
// in flight across the barrier.
static __device__ __forceinline__ void pipe_wait(int n) {
    if (n >= 3)      asm volatile("s_waitcnt vmcnt(3)" ::: "memory");
    else if (n == 2) asm volatile("s_waitcnt vmcnt(2)" ::: "memory");
    else if (n == 1) asm volatile("s_waitcnt vmcnt(1)" ::: "memory");
    else             asm volatile("s_waitcnt vmcnt(0)" ::: "memory");
    __builtin_amdgcn_sched_barrier(0);
    __builtin_amdgcn_s_barrier();
    __builtin_amdgcn_sched_barrier(0);
}

// Main fused cost+LSE loop. 3-term split-bf16 dot (Ah.Bh + Al.Bh + Ah.Bl).
// A (cols) streamed via 5-buffer LDS pipeline (4 tiles in flight); B (64 rows)
// held in registers. setprio(1) around MFMA cluster (T5).
// Caller must have staged tiles 0..3 (into bufs 0..3) before entry.
static __device__ __forceinline__ void lse_loop(
        const unsigned short* __restrict__ CPhi, const unsigned short* __restrict__ CPlo,
        char* ldsA, const float* lds_alpha,
        const bf16x8 (&bh)[4][2], const bf16x8 (&bl)[4][2],
        int jbase0, int wave, int lane, int swz, float (&m)[4], float (&s)[4]) {
    const int lrow = lane & 15, kgrp = lane >> 4;
    const int ro = lrow * 128;
    const int x0 = ((kgrp)     ^ (lrow & 7)) * 16;
    const int x1 = ((kgrp + 4) ^ (lrow & 7)) * 16;
#pragma unroll
    for (int ct = 0; ct < NCT; ++ct) {
        int w = NCT - 1 - ct; if (w > 3) w = 3;
        pipe_wait(w);                      // tile ct resident for ALL waves
        if (ct + 4 < NCT)                  // refill buf (ct+4)%5 == (ct-1)%5
            stage_tile(CPhi, CPlo, ldsA + ((ct + 4) % NBUF) * 4096,
                       jbase0 + (ct + 4) * 16, wave, swz);

        float4 av = *reinterpret_cast<const float4*>(lds_alpha + ct * 16 + kgrp * 4);
        const char* base = ldsA + (ct % NBUF) * 4096;
        bf16x8 ah0 = *reinterpret_cast<const bf16x8*>(base + ro + x0);
        bf16x8 ah1 = *reinterpret_cast<const bf16x8*>(base + ro + x1);
        bf16x8 al0 = *reinterpret_cast<const bf16x8*>(base + 2048 + ro + x0);
        bf16x8 al1 = *reinterpret_cast<const bf16x8*>(base + 2048 + ro + x1);

        __builtin_amdgcn_s_setprio(1);
        f32x4 acc[4];
#pragma unroll
        for (int it = 0; it < 4; ++it) {
            f32x4 a = {0.0f, 0.0f, 0.0f, 0.0f};
            a = __builtin_amdgcn_mfma_f32_16x16x32_bf16(ah0, bh[it][0], a, 0, 0, 0);
            a = __builtin_amdgcn_mfma_f32_16x16x32_bf16(ah1, bh[it][1], a, 0, 0, 0);
            a = __builtin_amdgcn_mfma_f32_16x16x32_bf16(al0, bh[it][0], a, 0, 0, 0);
            a = __builtin_amdgcn_mfma_f32_16x16x32_bf16(al1, bh[it][1], a, 0, 0, 0);
            a = __builtin_amdgcn_mfma_f32_16x16x32_bf16(ah0, bl[it][0], a, 0, 0, 0);
            a = __builtin_amdgcn_mfma_f32_16x16x32_bf16(ah1, bl[it][1], a, 0, 0, 0);
            acc[it] = a;
        }
        __builtin_amdgcn_s_setprio(0);

#pragma unroll
        for (int it = 0; it < 4; ++it) {
            float L0 = fmaf(TWOSCALE, acc[it][0], av.x);
            float L1 = fmaf(TWOSCALE, acc[it][1], av.y);
            float L2 = fmaf(TWOSCALE, acc[it][2], av.z);
            float L3 = fmaf(TWOSCALE, acc[it][3], av.w);
            float mx = fmaxf(fmaxf(L0, L1), fmaxf(L2, L3));
            float mn = fmaxf(m[it], mx);
            float rs = exp2fast(m[it] - mn);
            float e  = (exp2fast(L0 - mn) + exp2fast(L1 - mn)) +
                       (exp2fast(L2 - mn) + exp2fast(L3 - mn));
            s[it] = fmaf(s[it], rs, e);
            m[it] = mn;
        }
    }
}

static __device__ __forceinline__ void write_partials(
        float (&m)[4], float (&s)[4], float* __restrict__ pm, float* __restrict__ ps,
        const float* __restrict__ sqr2, int ck, int rowbase, int lane) {
    const int lrow = lane & 15, kgrp = lane >> 4;
#pragma unroll
    for (int off = 16; off < 64; off <<= 1) {
#pragma unroll
        for (int it = 0; it < 4; ++it) {
            float mo = __shfl_xor(m[it], off);
            float so = __shfl_xor(s[it], off);
            float mn = fmaxf(m[it], mo);
            s[it] = s[it] * exp2fast(m[it] - mn) + so * exp2fast(mo - mn);
            m[it] = mn;
        }
    }
    if (kgrp == 0) {
#pragma unroll
        for (int it = 0; it < 4; ++it) {
            int row = rowbase + it * 16 + lrow;
            pm[(size_t)ck * N + row] = m[it] - sqr2[row];
            ps[(size_t)ck * N + row] = s[it];
        }
    }
}

// uniform convergence self-check: sum the 32 blockDiff entries written by the
// previous col pass (stable during this dispatch; kernels serialize on stream)
static __device__ __forceinline__ bool conv_done(const float* __restrict__ bd) {
    float sd = 0.0f;
#pragma unroll
    for (int c = 0; c < 32; ++c) sd += bd[c];
    return sd * (1.0f / (float)N) < THRESH;
}

// ---------------- setup kernels ----------------
__global__ void norms_kernel(const float* __restrict__ S, const float* __restrict__ T,
                             float* __restrict__ sq_s2, float* __restrict__ sq_t2) {
    int t = blockIdx.x * blockDim.x + threadIdx.x;
    const float* p = (t < N) ? S : T;
    int r = t & (N - 1);
    const float4* row = reinterpret_cast<const float4*>(p + (size_t)r * KDIM);
    float acc = 0.0f;
#pragma unroll
    for (int q = 0; q < KDIM / 4; ++q) {
        float4 a = row[q];
        acc += a.x * a.x + a.y * a.y + a.z * a.z + a.w * a.w;
    }
    if (t < N) sq_s2[r] = acc * SCALE2; else sq_t2[r] = acc * SCALE2;
}

__global__ void init_kernel(float* u, float* v, float* blockDiff) {
    int t = blockIdx.x * blockDim.x + threadIdx.x;
    if (t < N) { u[t] = 0.0f; v[t] = 0.0f; }
    if (t < 128) blockDiff[t] = 1.0e9f;   // both ping-pong slots: "not converged"
}

__global__ void split_kernel(const float* __restrict__ S, const float* __restrict__ T,
                             unsigned short* __restrict__ Shi, unsigned short* __restrict__ Slo,
                             unsigned short* __restrict__ Thi, unsigned short* __restrict__ Tlo) {
    int t = blockIdx.x * 256 + threadIdx.x;
    const int half = (N * KDIM) / 4;
    const float* src = (t < half) ? S : T;
    unsigned short* dhi = (t < half) ? Shi : Thi;
    unsigned short* dlo = (t < half) ? Slo : Tlo;
    int e = (t < half) ? t : t - half;
    float4 x = reinterpret_cast<const float4*>(src)[e];
    unsigned short h0 = f2bf(x.x), h1 = f2bf(x.y), h2 = f2bf(x.z), h3 = f2bf(x.w);
    ushort4 hv = make_ushort4(h0, h1, h2, h3);
    ushort4 lv = make_ushort4(f2bf(x.x - bf2f(h0)), f2bf(x.y - bf2f(h1)),
                              f2bf(x.z - bf2f(h2)), f2bf(x.w - bf2f(h3)));
    reinterpret_cast<ushort4*>(dhi)[e] = hv;
    reinterpret_cast<ushort4*>(dlo)[e] = lv;
}

// ---------------- row pass (v->alpha reduce fused into prologue) ----------------
__global__ __launch_bounds__(256, 4) void row_lse(
        const unsigned short* __restrict__ CPhi, const unsigned short* __restrict__ CPlo,
        const unsigned short* __restrict__ RPhi, const unsigned short* __restrict__ RPlo,
        const float* __restrict__ pmV, const float* __restrict__ psV,  // prev col partials
        const float* __restrict__ sqc2,   // streamed-side norms
        const float* __restrict__ sqr2,   // held-side norms
        float* __restrict__ pm, float* __restrict__ ps,
        const float* __restrict__ bdPrev, int first) {
    if (!first && conv_done(bdPrev)) return;
    __shared__ __align__(16) char ldsA[NBUF * 4096];
    __shared__ __align__(16) float lds_alpha[COLSPAN];
    const int wave = threadIdx.x >> 6, lane = threadIdx.x & 63;
    const int lrow = lane & 15, kgrp = lane >> 4;
    const int ck = blockIdx.x & 31, rb = blockIdx.x >> 5;
    const int rowbase = rb * ROWS_PER_BLOCK + wave * 64;
    const int jbase0 = ck * COLSPAN;
    const int swz = (lane >> 3) * 128 + (((lane & 7) ^ ((lane >> 3) & 7)) << 4);

#pragma unroll
    for (int t = 0; t < 4; ++t)   // tiles 0..3 -> bufs 0..3
        stage_tile(CPhi, CPlo, ldsA + t * 4096, jbase0 + t * 16, wave, swz);

    // fused v->alpha reduce for this block's 256 streamed cols (overlaps stage)
    {
        int j = jbase0 + threadIdx.x;
        float a;
        if (first) {
            a = -sqc2[j];                 // v = 0
        } else {
            float mm = NEG_BIG, ss = 0.0f;
#pragma unroll
            for (int c = 0; c < NCHUNK; ++c) {
                float mc = pmV[(size_t)c * N + j];
                float sc = psV[(size_t)c * N + j];
                float mn = fmaxf(mm, mc);
                ss = ss * exp2fast(mm - mn) + sc * exp2fast(mc - mn);
                mm = mn;
            }
            float vnew = EPS_LOG_MU - EPSLN2 * (mm + log2fast(ss));
            a = fmaf(vnew, SCALE2, -sqc2[j]);
        }
        lds_alpha[threadIdx.x] = a;
    }

    bf16x8 bh[4][2], bl[4][2];
    load_held(RPhi, RPlo, rowbase, lrow, kgrp, bh, bl);

    float m[4] = {NEG_BIG, NEG_BIG, NEG_BIG, NEG_BIG};
    float s[4] = {0.0f, 0.0f, 0.0f, 0.0f};
    barrier_lds_only();   // alpha visible; prefetch stays in flight

    lse_loop(CPhi, CPlo, ldsA, lds_alpha, bh, bl, jbase0, wave, lane, swz, m, s);
    write_partials(m, s, pm, ps, sqr2, ck, rowbase, lane);
}

// ---------------- col pass (u-reduce fused; writes diff to bdCur) ----------------
__global__ __launch_bounds__(256, 4) void col_lse(
        const unsigned short* __restrict__ CPhi, const unsigned short* __restrict__ CPlo,
        const unsigned short* __restrict__ RPhi, const unsigned short* __restrict__ RPlo,
        const float* __restrict__ pm_in, const float* __restrict__ ps_in,
        const float* __restrict__ sqs2,   // streamed-side norms (alpha)
        float* __restrict__ u,            // rw by rb==0 blocks only
        const float* __restrict__ bdPrev,
        float* __restrict__ bdCur,
        const float* __restrict__ sqr2,   // held-side norms (partial write)
        float* __restrict__ pm, float* __restrict__ ps) {
    const int ck = blockIdx.x & 31, rb = blockIdx.x >> 5;
    if (conv_done(bdPrev)) {
        if (rb == 0 && threadIdx.x == 0) bdCur[ck] = 0.0f;   // latch convergence
        return;
    }
    __shared__ __align__(16) char ldsA[NBUF * 4096];
    __shared__ __align__(16) float lds_alpha[COLSPAN];
    __shared__ float wsum[4];
    const int wave = threadIdx.x >> 6, lane = threadIdx.x & 63;
    const int lrow = lane & 15, kgrp = lane >> 4;
    const int rowbase = rb * ROWS_PER_BLOCK + wave * 64;
    const int jbase0 = ck * COLSPAN;
    const int swz = (lane >> 3) * 128 + (((lane & 7) ^ ((lane >> 3) & 7)) << 4);

#pragma unroll
    for (int t = 0; t < 4; ++t)
        stage_tile(CPhi, CPlo, ldsA + t * 4096, jbase0 + t * 16, wave, swz);

    // fused u-reduce for this block's 256 streamed cols (overlaps stage latency)
    {
        int j = jbase0 + threadIdx.x;
        float mm = NEG_BIG, ss = 0.0f;
#pragma unroll
        for (int c = 0; c < NCHUNK; ++c) {
            float mc = pm_in[(size_t)c * N + j];
            float sc = ps_in[(size_t)c * N + j];
            float mn = fmaxf(mm, mc);
            ss = ss * exp2fast(mm - mn) + sc * exp2fast(mc - mn);
            mm = mn;
        }
        float unew = EPS_LOG_MU - EPSLN2 * (mm + log2fast(ss));
        lds_alpha[threadIdx.x] = fmaf(unew, SCALE2, -sqs2[j]);
        if (rb == 0) {
            float d = fabsf(unew - u[j]);
            u[j] = unew;
#pragma unroll
            for (int off = 32; off; off >>= 1) d += __shfl_xor(d, off);
            if (lane == 0) wsum[wave] = d;
        }
    }

    bf16x8 bh[4][2], bl[4][2];
    load_held(RPhi, RPlo, rowbase, lrow, kgrp, bh, bl);

    float m[4] = {NEG_BIG, NEG_BIG, NEG_BIG, NEG_BIG};
    float s[4] = {0.0f, 0.0f, 0.0f, 0.0f};
    barrier_lds_only();
    if (rb == 0 && threadIdx.x == 0)
        bdCur[ck] = wsum[0] + wsum[1] + wsum[2] + wsum[3];

    lse_loop(CPhi, CPlo, ldsA, lds_alpha, bh, bl, jbase0, wave, lane, swz, m, s);
    write_partials(m, s, pm, ps, sqr2, ck, rowbase, lane);
}

// ---------------- post-loop: reduce final pmB/psB -> v ----------------
__global__ __launch_bounds__(256) void v_final(const float* __restrict__ pm,
                                               const float* __restrict__ ps,
                                               float* __restrict__ v) {
    int j = blockIdx.x * 256 + threadIdx.x;
    float m = NEG_BIG, s = 0.0f;
#pragma unroll
    for (int c = 0; c < NCHUNK; ++c) {
        float mc = pm[(size_t)c * N + j];
        float sc = ps[(size_t)c * N + j];
        float mn = fmaxf(m, mc);
        s = s * exp2fast(m - mn) + sc * exp2fast(mc - mn);
        m = mn;
    }
    v[j] = EPS_LOG_MU - EPSLN2 * (m + log2fast(s));
}

// ---------------- final: sum(exp((u+v-c)/eps) * c), same approx cost ----------------
__global__ __launch_bounds__(256, 4) void plan_mfma(
        const unsigned short* __restrict__ CPhi, const unsigned short* __restrict__ CPlo,  // T
        const unsigned short* __restrict__ RPhi, const unsigned short* __restrict__ RPlo,  // S
        const float* __restrict__ u, const float* __restrict__ v,
        const float* __restrict__ sqr2, const float* __restrict__ sqc2,
        float* __restrict__ part) {
    __shared__ __align__(16) char ldsA[NBUF * 4096];
    __shared__ __align__(16) float lds_v2[COLSPAN];
    __shared__ __align__(16) float lds_sqc[COLSPAN];
    __shared__ float wsum[4];
    const int wave = threadIdx.x >> 6, lane = threadIdx.x & 63;
    const int lrow = lane & 15, kgrp = lane >> 4;
    const int ck = blockIdx.x & 31, rb = blockIdx.x >> 5;
    const int rowbase = rb * ROWS_PER_BLOCK + wave * 64;
    const int jbase0 = ck * COLSPAN;
    const int swz = (lane >> 3) * 128 + (((lane & 7) ^ ((lane >> 3) & 7)) << 4);

#pragma unroll
    for (int t = 0; t < 4; ++t)
        stage_tile(CPhi, CPlo, ldsA + t * 4096, jbase0 + t * 16, wave, swz);
    lds_v2[threadIdx.x]  = v[jbase0 + threadIdx.x] * SCALE2;
    lds_sqc[threadIdx.x] = sqc2[jbase0 + threadIdx.x];

    bf16x8 bh[4][2], bl[4][2];
    load_held(RPhi, RPlo, rowbase, lrow, kgrp, bh, bl);

    float sqr_i[4], u2_i[4];
#pragma unroll
    for (int it = 0; it < 4; ++it) {
        int row = rowbase + it * 16 + lrow;
        sqr_i[it] = sqr2[row];
        u2_i[it]  = u[row] * SCALE2;
    }

    float lsum = 0.0f;
    barrier_lds_only();

    const int ro = lrow * 128;
    const int x0 = ((kgrp)     ^ (lrow & 7)) * 16;
    const int x1 = ((kgrp + 4) ^ (lrow & 7)) * 16;
#pragma unroll
    for (int ct = 0; ct < NCT; ++ct) {
        int w = NCT - 1 - ct; if (w > 3) w = 3;
        pipe_wait(w);
        if (ct + 4 < NCT)
            stage_tile(CPhi, CPlo, ldsA + ((ct + 4) % NBUF) * 4096,
                       jbase0 + (ct + 4) * 16, wave, swz);

        float4 v2 = *reinterpret_cast<const float4*>(lds_v2 + ct * 16 + kgrp * 4);
        float4 sc = *reinterpret_cast<const float4*>(lds_sqc + ct * 16 + kgrp * 4);
        const char* base = ldsA + (ct % NBUF) * 4096;
        bf16x8 ah0 = *reinterpret_cast<const bf16x8*>(base + ro + x0);
        bf16x8 ah1 = *reinterpret_cast<const bf16x8*>(base + ro + x1);
        bf16x8 al0 = *reinterpret_cast<const bf16x8*>(base + 2048 + ro + x0);
        bf16x8 al1 = *reinterpret_cast<const bf16x8*>(base + 2048 + ro + x1);

        __builtin_amdgcn_s_setprio(1);
        f32x4 acc[4];
#pragma unroll
        for (int it = 0; it < 4; ++it) {
            f32x4 a = {0.0f, 0.0f, 0.0f, 0.0f};
            a = __builtin_amdgcn_mfma_f32_16x16x32_bf16(ah0, bh[it][0], a, 0, 0, 0);
            a = __builtin_amdgcn_mfma_f32_16x16x32_bf16(ah1, bh[it][1], a, 0, 0, 0);
            a = __builtin_amdgcn_mfma_f32_16x16x32_bf16(al0, bh[it][0], a, 0, 0, 0);
            a = __builtin_amdgcn_mfma_f32_16x16x32_bf16(al1, bh[it][1], a, 0, 0, 0);
            a = __builtin_amdgcn_mfma_f32_16x16x32_bf16(ah0, bl[it][0], a, 0, 0, 0);
            a = __builtin_amdgcn_mfma_f32_16x16x32_bf16(ah1, bl[it][1], a, 0, 0, 0);
            acc[it] = a;
        }
        __builtin_amdgcn_s_setprio(0);

        float vs[4] = {v2.x, v2.y, v2.z, v2.w};
        float ss[4] = {sc.x, sc.y, sc.z, sc.w};
#pragma unroll
        for (int it = 0; it < 4; ++it) {
#pragma unroll
            for (int r = 0; r < 4; ++r) {
                float c2 = fmaxf(sqr_i[it] + ss[r] - TWOSCALE * acc[it][r], 0.0f);
                lsum = fmaf(exp2fast(u2_i[it] + vs[r] - c2), c2, lsum);
            }
        }
    }
    lsum *= INV_SCALE2;

#pragma unroll
    for (int off = 32; off; off >>= 1) lsum += __shfl_xor(lsum, off);
    if (lane == 0) wsum[wave] = lsum;
    __syncthreads();
    if (threadIdx.x == 0)
        part[blockIdx.x] = wsum[0] + wsum[1] + wsum[2] + wsum[3];
}

__global__ void final_reduce(const float* __restrict__ part, float* __restrict__ out) {
    int t = threadIdx.x;
    float sum = 0.0f;
    for (int i = t; i < 1024; i += 256) sum += part[i];
#pragma unroll
    for (int off = 32; off; off >>= 1) sum += __shfl_xor(sum, off);
    __shared__ float wsum[4];
    int lane = t & 63, wave = t >> 6;
    if (lane == 0) wsum[wave] = sum;
    __syncthreads();
    if (t == 0) out[0] = wsum[0] + wsum[1] + wsum[2] + wsum[3];
}

extern "C" void kernel_launch(void* const* d_in, const int* in_sizes, int n_in,
                              void* d_out, int out_size, void* d_ws, size_t ws_size,
                              hipStream_t stream) {
    const float* S = (const float*)d_in[0];
    const float* T = (const float*)d_in[1];
    float* out = (float*)d_out;

    // workspace (~8.3 MB)
    unsigned short* us = (unsigned short*)d_ws;
    unsigned short* Shi = us;
    unsigned short* Slo = us + (size_t)N * KDIM;
    unsigned short* Thi = us + (size_t)2 * N * KDIM;
    unsigned short* Tlo = us + (size_t)3 * N * KDIM;
    float* w = (float*)(us + (size_t)4 * N * KDIM);
    size_t off = 0;
    float* sq_s2     = w + off; off += N;
    float* sq_t2     = w + off; off += N;
    float* u         = w + off; off += N;
    float* v         = w + off; off += N;
    float* pmA       = w + off; off += (size_t)NCHUNK * N;
    float* psA       = w + off; off += (size_t)NCHUNK * N;
    float* pmB       = w + off; off += (size_t)NCHUNK * N;
    float* psB       = w + off; off += (size_t)NCHUNK * N;
    float* blockDiff = w + off; off += 128;   // 2 ping-pong slots of 64
    float* part      = w + off; off += 1024;

    hipLaunchKernelGGL(norms_kernel, dim3(64),   dim3(256), 0, stream, S, T, sq_s2, sq_t2);
    hipLaunchKernelGGL(init_kernel,  dim3(32),   dim3(256), 0, stream, u, v, blockDiff);
    hipLaunchKernelGGL(split_kernel, dim3(1024), dim3(256), 0, stream, S, T, Shi, Slo, Thi, Tlo);

    const int LSE_BLOCKS = (N / ROWS_PER_BLOCK) * NCHUNK;   // 32*32 = 1024
    for (int it = 0; it < 50; ++it) {
        float* bdPrev = blockDiff + ((it + 1) & 1) * 64;
        float* bdCur  = blockDiff + (it & 1) * 64;
        // row pass: stream T cols vs held S rows; v->alpha reduce fused
        hipLaunchKernelGGL(row_lse, dim3(LSE_BLOCKS), dim3(256), 0, stream,
                           Thi, Tlo, Shi, Slo, pmB, psB, sq_t2, sq_s2,
                           pmA, psA, bdPrev, it == 0 ? 1 : 0);
        // col pass: stream S cols vs held T rows; u-reduce fused; diff -> bdCur
        hipLaunchKernelGGL(col_lse, dim3(LSE_BLOCKS), dim3(256), 0, stream,
                           Shi, Slo, Thi, Tlo, pmA, psA, sq_s2, u,
                           bdPrev, bdCur, sq_t2, pmB, psB);
    }

    hipLaunchKernelGGL(v_final, dim3(32), dim3(256), 0, stream, pmB, psB, v);
    hipLaunchKernelGGL(plan_mfma, dim3(LSE_BLOCKS), dim3(256), 0, stream,
                       Thi, Tlo, Shi, Slo, u, v, sq_s2, sq_t2, part);
    hipLaunchKernelGGL(final_reduce, dim3(1), dim3(256), 0, stream, part, out);
}